// Round 1
// baseline (10899.929 us; speedup 1.0000x reference)
//
#include <hip/hip_runtime.h>

#define IMG 512
#define CCH 128
#define NHEAD 4
#define HDIM 32
#define NTOK 64
#define SHIFT_AMT 4

// LDS budget (59136 B < 64 KB -> 2 blocks/CU):
//   xs  : 64 x 132 fp32 = 33792 B   (window tokens, +4 pad keeps float4 alignment)
//   u0  : max(q+k = 2*64*33, ps = 64*65) = 4224 fp32 = 16896 B  (q/k aliased with scores)
//   u1  : max(v = 64*33, oh = 64*33) = 2112 fp32 = 8448 B       (v aliased with per-head out)
__global__ __launch_bounds__(256)
void win_attn_fp32(const float* __restrict__ x,
                   const float* __restrict__ qkv_w,
                   const float* __restrict__ qkv_b,
                   const float* __restrict__ proj_w,
                   const float* __restrict__ proj_b,
                   const float* __restrict__ bias_table,
                   float* __restrict__ out)
{
    __shared__ float xs[NTOK][CCH + 4];
    __shared__ float u0[2 * NTOK * 33];   // q,k | ps
    __shared__ float u1[NTOK * 33];       // v | oh

    float (*qs)[33] = (float (*)[33])u0;
    float (*ks)[33] = (float (*)[33])(u0 + NTOK * 33);
    float (*ps)[65] = (float (*)[65])u0;
    float (*vs)[33] = (float (*)[33])u1;
    float (*oh)[33] = (float (*)[33])u1;

    const int tid = threadIdx.x;
    const int widx = blockIdx.x;
    const int b  = widx >> 12;
    const int wh = (widx >> 6) & 63;
    const int ww = widx & 63;

    const int lane_c = tid & 31;   // 0..31
    const int lane_r = tid >> 5;   // 0..7

    // ---- Phase A: load rolled window into LDS (roll folded into the index) ----
    {
        const int c0 = lane_c * 4;
        #pragma unroll
        for (int rr = 0; rr < 8; ++rr) {
            const int row = lane_r + rr * 8;
            const int i = row >> 3, j = row & 7;
            const int h = (wh * 8 + i + SHIFT_AMT) & (IMG - 1);
            const int w = (ww * 8 + j + SHIFT_AMT) & (IMG - 1);
            const float4 v4 = *(const float4*)(x + ((((size_t)b * IMG + h) * IMG + w) * CCH + c0));
            *(float4*)&xs[row][c0] = v4;
        }
    }
    __syncthreads();

    const float scale = 0.17677669529663687f;  // 1/sqrt(32)

    // persistent projection accumulators: rows lane_r+8rr, cols cb*32+lane_c
    float pacc[4][8];
    #pragma unroll
    for (int cb = 0; cb < 4; ++cb)
        #pragma unroll
        for (int rr = 0; rr < 8; ++rr) pacc[cb][rr] = 0.f;

    for (int hh = 0; hh < NHEAD; ++hh) {
        // ---- B1: q,k,v for head hh (register-blocked: 24 accumulators, w loaded once/c) ----
        {
            const int qc = hh * HDIM + lane_c;
            const float bq = qkv_b[qc];
            const float bk = qkv_b[CCH + qc];
            const float bv = qkv_b[2 * CCH + qc];
            float accq[8], acck[8], accv[8];
            #pragma unroll
            for (int rr = 0; rr < 8; ++rr) { accq[rr] = bq; acck[rr] = bk; accv[rr] = bv; }
            for (int c = 0; c < CCH; ++c) {
                const float wq = qkv_w[c * 3 * CCH + qc];
                const float wk = qkv_w[c * 3 * CCH + CCH + qc];
                const float wv = qkv_w[c * 3 * CCH + 2 * CCH + qc];
                #pragma unroll
                for (int rr = 0; rr < 8; ++rr) {
                    const float xv = xs[lane_r + rr * 8][c];
                    accq[rr] = fmaf(xv, wq, accq[rr]);
                    acck[rr] = fmaf(xv, wk, acck[rr]);
                    accv[rr] = fmaf(xv, wv, accv[rr]);
                }
            }
            #pragma unroll
            for (int rr = 0; rr < 8; ++rr) {
                const int row = lane_r + rr * 8;
                qs[row][lane_c] = accq[rr];
                ks[row][lane_c] = acck[rr];
                vs[row][lane_c] = accv[rr];
            }
        }
        __syncthreads();

        // ---- B2: S = scale*Q@K^T + bias, computed to regs (ps aliases q/k storage) ----
        {
            const int m  = tid & 63;
            const int n0 = tid >> 6;          // 0..3
            float kreg[HDIM];
            #pragma unroll
            for (int d = 0; d < HDIM; ++d) kreg[d] = ks[m][d];
            const int im = m >> 3, jm = m & 7;
            float sreg[16];
            #pragma unroll
            for (int nb = 0; nb < 16; ++nb) {
                const int n = n0 + nb * 4;
                float acc = 0.f;
                #pragma unroll
                for (int d = 0; d < HDIM; ++d)
                    acc = fmaf(qs[n][d], kreg[d], acc);
                const int in_ = n >> 3, jn = n & 7;
                const int rel = (in_ - im + 7) * 15 + (jn - jm + 7);
                sreg[nb] = acc * scale + bias_table[rel * NHEAD + hh];
            }
            __syncthreads();   // all q/k reads done; safe to overwrite with ps
            #pragma unroll
            for (int nb = 0; nb < 16; ++nb)
                ps[n0 + nb * 4][m] = sreg[nb];
        }
        __syncthreads();

        // ---- B2b: row-wise softmax on ps (4 threads per row) ----
        {
            const int r  = tid >> 2;
            const int p0 = (tid & 3) * 16;
            float ev[16];
            float mx = -3.0e38f;
            #pragma unroll
            for (int c2 = 0; c2 < 16; ++c2) mx = fmaxf(mx, ps[r][p0 + c2]);
            mx = fmaxf(mx, __shfl_xor(mx, 1));
            mx = fmaxf(mx, __shfl_xor(mx, 2));
            float sum = 0.f;
            #pragma unroll
            for (int c2 = 0; c2 < 16; ++c2) { ev[c2] = __expf(ps[r][p0 + c2] - mx); sum += ev[c2]; }
            sum += __shfl_xor(sum, 1);
            sum += __shfl_xor(sum, 2);
            const float inv = 1.f / sum;
            #pragma unroll
            for (int c2 = 0; c2 < 16; ++c2) ps[r][p0 + c2] = ev[c2] * inv;
        }
        __syncthreads();

        // ---- B3: O_h = P @ V (to regs) ----
        float oacc[8];
        {
            #pragma unroll
            for (int rr = 0; rr < 8; ++rr) oacc[rr] = 0.f;
            for (int m = 0; m < NTOK; ++m) {
                const float vv = vs[m][lane_c];
                #pragma unroll
                for (int rr = 0; rr < 8; ++rr)
                    oacc[rr] = fmaf(ps[lane_r + rr * 8][m], vv, oacc[rr]);
            }
        }
        __syncthreads();   // v reads done; safe to overwrite with oh
        #pragma unroll
        for (int rr = 0; rr < 8; ++rr)
            oh[lane_r + rr * 8][lane_c] = oacc[rr];
        __syncthreads();

        // ---- B4: partial projection for this head's 32 channels ----
        {
            for (int c = 0; c < HDIM; ++c) {
                const int wrow = (hh * HDIM + c) * CCH;
                float wv[4];
                #pragma unroll
                for (int cb = 0; cb < 4; ++cb) wv[cb] = proj_w[wrow + cb * 32 + lane_c];
                #pragma unroll
                for (int rr = 0; rr < 8; ++rr) {
                    const float ov = oh[lane_r + rr * 8][c];
                    #pragma unroll
                    for (int cb = 0; cb < 4; ++cb)
                        pacc[cb][rr] = fmaf(ov, wv[cb], pacc[cb][rr]);
                }
            }
        }
        __syncthreads();   // oh reads done before next head's B1 overwrites q/k/v
    }

    // ---- Phase C: add proj bias, store with roll folded into the index ----
    {
        #pragma unroll
        for (int cb = 0; cb < 4; ++cb) {
            const int col = cb * 32 + lane_c;
            const float pb = proj_b[col];
            #pragma unroll
            for (int rr = 0; rr < 8; ++rr) {
                const int row = lane_r + rr * 8;
                const int i = row >> 3, j = row & 7;
                const int h = (wh * 8 + i + SHIFT_AMT) & (IMG - 1);
                const int w = (ww * 8 + j + SHIFT_AMT) & (IMG - 1);
                out[(((size_t)b * IMG + h) * IMG + w) * CCH + col] = pacc[cb][rr] + pb;
            }
        }
    }
}

extern "C" void kernel_launch(void* const* d_in, const int* in_sizes, int n_in,
                              void* d_out, int out_size, void* d_ws, size_t ws_size,
                              hipStream_t stream)
{
    const float* x        = (const float*)d_in[0];
    const float* qkv_w    = (const float*)d_in[1];
    const float* qkv_b    = (const float*)d_in[2];
    const float* proj_w   = (const float*)d_in[3];
    const float* proj_b   = (const float*)d_in[4];
    const float* bias_tab = (const float*)d_in[5];
    float* out = (float*)d_out;

    dim3 grid(4 * 64 * 64);   // B * nH * nW windows
    dim3 block(256);
    hipLaunchKernelGGL(win_attn_fp32, grid, block, 0, stream,
                       x, qkv_w, qkv_b, proj_w, proj_b, bias_tab, out);
}

// Round 2
// 1398.093 us; speedup vs baseline: 7.7963x; 7.7963x over previous
//
#include <hip/hip_runtime.h>

#define IMG 512
#define CCH 128
#define NHEAD 4
#define HDIM 32
#define NTOK 64
#define SHIFT_AMT 4

typedef __attribute__((ext_vector_type(8))) short bf16x8;
typedef __attribute__((ext_vector_type(4))) short short4v;
typedef __attribute__((ext_vector_type(4))) float f32x4;

__device__ __forceinline__ short f2bf(float f) {
    unsigned u = __float_as_uint(f);
    unsigned r = (u + 0x7FFFu + ((u >> 16) & 1u)) >> 16;
    return (short)r;
}

// ---------------- pre-kernel: transpose + convert weights to bf16 in ws ----------------
// ws layout: [0)            wqkvt bf16 [384][128]  (out-ch major, in-ch contiguous)
//            [49152 elems)  wpt   bf16 [128][128]
__global__ __launch_bounds__(256)
void cvt_weights(const float* __restrict__ qkv_w, const float* __restrict__ proj_w,
                 short* __restrict__ wqkvt, short* __restrict__ wpt)
{
    int idx = blockIdx.x * 256 + threadIdx.x;   // 0 .. 65535
    if (idx < 384 * 128) {
        int n = idx >> 7, k = idx & 127;
        wqkvt[idx] = f2bf(qkv_w[k * 384 + n]);
    } else {
        int i2 = idx - 384 * 128;
        int n = i2 >> 7, k = i2 & 127;
        wpt[i2] = f2bf(proj_w[k * 128 + n]);
    }
}

// ---------------- main kernel: one block (256 thr, 4 waves) per 8x8 window ----------------
__global__ __launch_bounds__(256, 2)
void win_attn_mfma(const float* __restrict__ x,
                   const short* __restrict__ wqkvt,
                   const float* __restrict__ qkv_b,
                   const short* __restrict__ wpt,
                   const float* __restrict__ proj_b,
                   const float* __restrict__ bias_table,
                   float* __restrict__ out)
{
    // LDS: 34816 (qs+ks) + 18432 (vt) + 9216 (ps) = 62464 B -> 2 blocks/CU
    __shared__ __align__(16) short qs[NTOK][136];   // q row-major [tok][ch]; aliased as os in phase 3
    __shared__ __align__(16) short ks[NTOK][136];   // k row-major [tok][ch]
    __shared__ __align__(16) short vt[CCH][72];     // v transposed [ch][tok]
    __shared__ __align__(16) short ps[NTOK][72];    // P row-major [query][key]

    const int tid  = threadIdx.x;
    const int wv   = tid >> 6;        // wave 0..3
    const int lane = tid & 63;
    const int l16  = lane & 15;
    const int q16  = lane >> 4;       // quad 0..3

    const int widx = blockIdx.x;
    const int b  = widx >> 12;
    const int wh = (widx >> 6) & 63;
    const int ww = widx & 63;

    const f32x4 zf = {0.f, 0.f, 0.f, 0.f};

    // ---------------- Phase 1: QKV GEMM. wave wv owns output channels [96wv, 96wv+96) ----------------
    // token row base offsets (in floats) for this lane's 4 M-tiles (roll folded in)
    size_t pixoff[4];
    #pragma unroll
    for (int mt = 0; mt < 4; ++mt) {
        const int tok = mt * 16 + l16;
        const int hh_ = (wh * 8 + (tok >> 3) + SHIFT_AMT) & (IMG - 1);
        const int ww_ = (ww * 8 + (tok & 7)  + SHIFT_AMT) & (IMG - 1);
        pixoff[mt] = (((size_t)b * IMG + hh_) * IMG + ww_) * CCH;
    }

    f32x4 acc1[6][4];
    #pragma unroll
    for (int nt = 0; nt < 6; ++nt)
        #pragma unroll
        for (int mt = 0; mt < 4; ++mt) acc1[nt][mt] = zf;

    #pragma unroll
    for (int kk = 0; kk < 4; ++kk) {
        bf16x8 a[4];
        #pragma unroll
        for (int mt = 0; mt < 4; ++mt) {
            const float* p = x + pixoff[mt] + kk * 32 + q16 * 8;
            const float4 f0 = *(const float4*)p;
            const float4 f1 = *(const float4*)(p + 4);
            bf16x8 av;
            av[0] = f2bf(f0.x); av[1] = f2bf(f0.y); av[2] = f2bf(f0.z); av[3] = f2bf(f0.w);
            av[4] = f2bf(f1.x); av[5] = f2bf(f1.y); av[6] = f2bf(f1.z); av[7] = f2bf(f1.w);
            a[mt] = av;
        }
        #pragma unroll
        for (int nt = 0; nt < 6; ++nt) {
            const short* wp = wqkvt + (size_t)(wv * 96 + nt * 16 + l16) * 128 + kk * 32 + q16 * 8;
            const bf16x8 bfr = *(const bf16x8*)wp;
            #pragma unroll
            for (int mt = 0; mt < 4; ++mt)
                acc1[nt][mt] = __builtin_amdgcn_mfma_f32_16x16x32_bf16(a[mt], bfr, acc1[nt][mt], 0, 0, 0);
        }
    }

    // epilogue: add bias, write bf16 to LDS (q/k row-major, v transposed)
    #pragma unroll
    for (int nt = 0; nt < 6; ++nt) {
        const int n0  = wv * 96 + nt * 16;     // wave-uniform
        const int col = n0 + l16;
        const float bias = qkv_b[col];
        if (n0 < 128) {                        // q
            #pragma unroll
            for (int mt = 0; mt < 4; ++mt)
                #pragma unroll
                for (int r = 0; r < 4; ++r)
                    qs[mt * 16 + q16 * 4 + r][col] = f2bf(acc1[nt][mt][r] + bias);
        } else if (n0 < 256) {                 // k
            #pragma unroll
            for (int mt = 0; mt < 4; ++mt)
                #pragma unroll
                for (int r = 0; r < 4; ++r)
                    ks[mt * 16 + q16 * 4 + r][col - 128] = f2bf(acc1[nt][mt][r] + bias);
        } else {                               // v -> vt[ch][tok], 4 consecutive tokens packed
            #pragma unroll
            for (int mt = 0; mt < 4; ++mt) {
                short4v pk;
                pk[0] = f2bf(acc1[nt][mt][0] + bias);
                pk[1] = f2bf(acc1[nt][mt][1] + bias);
                pk[2] = f2bf(acc1[nt][mt][2] + bias);
                pk[3] = f2bf(acc1[nt][mt][3] + bias);
                *(short4v*)&vt[col - 256][mt * 16 + q16 * 4] = pk;
            }
        }
    }
    __syncthreads();

    // ---------------- Phase 2: attention. wave wv owns query M-tile [16wv, 16wv+16) ----------------
    const float scale = 0.17677669529663687f;  // 1/sqrt(32)
    f32x4 oacc[8];                             // [head][ntv 0..1] -> 32 fp32 regs
    #pragma unroll
    for (int i = 0; i < 8; ++i) oacc[i] = zf;

    const int qrow_base = wv * 16 + q16 * 4;   // + r = global query token

    #pragma unroll
    for (int h = 0; h < NHEAD; ++h) {
        // S = scale * Q K^T + bias  (one MFMA per 16x16 tile, K = 32 = hd)
        const bf16x8 aq = *(const bf16x8*)&qs[wv * 16 + l16][h * 32 + q16 * 8];
        f32x4 s[4];
        #pragma unroll
        for (int nt = 0; nt < 4; ++nt) {
            const bf16x8 bk = *(const bf16x8*)&ks[nt * 16 + l16][h * 32 + q16 * 8];
            s[nt] = __builtin_amdgcn_mfma_f32_16x16x32_bf16(aq, bk, zf, 0, 0, 0);
        }
        // bias + softmax (rows live in 16-lane groups; shuffle-xor 1/2/4/8)
        #pragma unroll
        for (int r = 0; r < 4; ++r) {
            const int qrow = qrow_base + r;
            const int qi = qrow >> 3, qj = qrow & 7;
            #pragma unroll
            for (int nt = 0; nt < 4; ++nt) {
                const int kn = nt * 16 + l16;
                const int rel = (qi - (kn >> 3) + 7) * 15 + (qj - (kn & 7) + 7);
                s[nt][r] = s[nt][r] * scale + bias_table[rel * NHEAD + h];
            }
            float mx = fmaxf(fmaxf(s[0][r], s[1][r]), fmaxf(s[2][r], s[3][r]));
            mx = fmaxf(mx, __shfl_xor(mx, 1));
            mx = fmaxf(mx, __shfl_xor(mx, 2));
            mx = fmaxf(mx, __shfl_xor(mx, 4));
            mx = fmaxf(mx, __shfl_xor(mx, 8));
            float sum = 0.f;
            #pragma unroll
            for (int nt = 0; nt < 4; ++nt) { s[nt][r] = __expf(s[nt][r] - mx); sum += s[nt][r]; }
            sum += __shfl_xor(sum, 1);
            sum += __shfl_xor(sum, 2);
            sum += __shfl_xor(sum, 4);
            sum += __shfl_xor(sum, 8);
            const float inv = 1.f / sum;
            #pragma unroll
            for (int nt = 0; nt < 4; ++nt) s[nt][r] *= inv;
        }
        // P -> LDS (row-major bf16), own rows only -> no barrier
        #pragma unroll
        for (int nt = 0; nt < 4; ++nt)
            #pragma unroll
            for (int r = 0; r < 4; ++r)
                ps[qrow_base + r][nt * 16 + l16] = f2bf(s[nt][r]);

        // O_h += P @ V   (A from ps, B from vt; K = 64 -> 2 iters)
        #pragma unroll
        for (int kk = 0; kk < 2; ++kk) {
            const bf16x8 ap = *(const bf16x8*)&ps[wv * 16 + l16][kk * 32 + q16 * 8];
            #pragma unroll
            for (int ntv = 0; ntv < 2; ++ntv) {
                const bf16x8 bv = *(const bf16x8*)&vt[h * 32 + ntv * 16 + l16][kk * 32 + q16 * 8];
                oacc[h * 2 + ntv] = __builtin_amdgcn_mfma_f32_16x16x32_bf16(ap, bv, oacc[h * 2 + ntv], 0, 0, 0);
            }
        }
    }

    // ---------------- Phase 3: projection ----------------
    __syncthreads();                    // qs reads done everywhere; safe to overwrite as os
    short (*os)[136] = qs;
    #pragma unroll
    for (int h = 0; h < NHEAD; ++h)
        #pragma unroll
        for (int ntv = 0; ntv < 2; ++ntv)
            #pragma unroll
            for (int r = 0; r < 4; ++r)
                os[qrow_base + r][h * 32 + ntv * 16 + l16] = f2bf(oacc[h * 2 + ntv][r]);
    __syncthreads();

    // wave wv owns out channels [32wv, 32wv+32): 2 N-tiles x 4 M-tiles
    f32x4 c2[2][4];
    #pragma unroll
    for (int nt = 0; nt < 2; ++nt)
        #pragma unroll
        for (int mt = 0; mt < 4; ++mt) c2[nt][mt] = zf;

    #pragma unroll
    for (int kk = 0; kk < 4; ++kk) {
        bf16x8 am[4];
        #pragma unroll
        for (int mt = 0; mt < 4; ++mt)
            am[mt] = *(const bf16x8*)&os[mt * 16 + l16][kk * 32 + q16 * 8];
        #pragma unroll
        for (int nt = 0; nt < 2; ++nt) {
            const short* wp = wpt + (size_t)(wv * 32 + nt * 16 + l16) * 128 + kk * 32 + q16 * 8;
            const bf16x8 bw = *(const bf16x8*)wp;
            #pragma unroll
            for (int mt = 0; mt < 4; ++mt)
                c2[nt][mt] = __builtin_amdgcn_mfma_f32_16x16x32_bf16(am[mt], bw, c2[nt][mt], 0, 0, 0);
        }
    }

    // epilogue: + proj_b, store fp32 with roll folded in
    #pragma unroll
    for (int nt = 0; nt < 2; ++nt) {
        const int col = wv * 32 + nt * 16 + l16;
        const float pb = proj_b[col];
        #pragma unroll
        for (int mt = 0; mt < 4; ++mt) {
            #pragma unroll
            for (int r = 0; r < 4; ++r) {
                const int tok = mt * 16 + q16 * 4 + r;
                const int hh_ = (wh * 8 + (tok >> 3) + SHIFT_AMT) & (IMG - 1);
                const int ww_ = (ww * 8 + (tok & 7)  + SHIFT_AMT) & (IMG - 1);
                out[(((size_t)b * IMG + hh_) * IMG + ww_) * CCH + col] = c2[nt][mt][r] + pb;
            }
        }
    }
}

extern "C" void kernel_launch(void* const* d_in, const int* in_sizes, int n_in,
                              void* d_out, int out_size, void* d_ws, size_t ws_size,
                              hipStream_t stream)
{
    const float* x        = (const float*)d_in[0];
    const float* qkv_w    = (const float*)d_in[1];
    const float* qkv_b    = (const float*)d_in[2];
    const float* proj_w   = (const float*)d_in[3];
    const float* proj_b   = (const float*)d_in[4];
    const float* bias_tab = (const float*)d_in[5];
    float* out = (float*)d_out;

    short* wqkvt = (short*)d_ws;            // 384*128 bf16
    short* wpt   = wqkvt + 384 * 128;       // 128*128 bf16  (total 131072 B of ws)

    hipLaunchKernelGGL(cvt_weights, dim3(256), dim3(256), 0, stream,
                       qkv_w, proj_w, wqkvt, wpt);
    hipLaunchKernelGGL(win_attn_mfma, dim3(4 * 64 * 64), dim3(256), 0, stream,
                       x, wqkvt, qkv_b, wpt, proj_b, bias_tab, out);
}